// Round 1
// baseline (444.864 us; speedup 1.0000x reference)
//
#include <hip/hip_runtime.h>
#include <hip/hip_bf16.h>

// LocalAggregator (GAT-style, 4 relation types selected by adj) — fused
// flash-style fp32 kernel. No workspace needed: the time-embedding column
// (d=127) is computed on the fly while staging LDS tiles.
//
// Per block: one (batch b, i-tile of 128 rows). Loop over 8 j-tiles of 64.
//   e-phase: acc[ii][jj][k] += (h_i*h_j)*a_k  (all 4 k, select by adj after
//            the d-loop — avoids runtime-k register indexing / scratch)
//   online softmax with NEG_INF=-9e15 (matches JAX all-masked-row semantics)
//   PV via p staged in LDS, remapped thread layout (8 rows x 4 d) to balance
//   LDS b128 traffic against FMA issue.

namespace {
constexpr int kB = 64;
constexpr int kN = 512;
constexpr int kD = 128;
constexpr int TI = 128;
constexpr int TJ = 64;
constexpr int PAD = 132;        // +4 floats: breaks 512B-stride bank aliasing
constexpr float kNegInf = -9e15f;
constexpr float kAlpha = 0.2f;  // leaky_relu slope
}

__launch_bounds__(512, 1)
__global__ void gat_flash_f32(const float* __restrict__ hidden,
                              const int*   __restrict__ adj,
                              const float* __restrict__ times,
                              const float* __restrict__ a0,
                              const float* __restrict__ a1,
                              const float* __restrict__ a2,
                              const float* __restrict__ a3,
                              const float* __restrict__ p0p,
                              const float* __restrict__ p1p,
                              float* __restrict__ out)
{
    __shared__ float sh_hi[TI][PAD];
    __shared__ float sh_hj[TJ][PAD];
    __shared__ float sh_p [TI][TJ];
    __shared__ float sh_a [4][kD];
    __shared__ float sh_scale[TI];
    __shared__ float sh_l[TI];

    const int t  = threadIdx.x;
    const int b  = blockIdx.x >> 2;
    const int i0 = (blockIdx.x & 3) * TI;

    const float p0 = p0p[0];
    const float p1 = p1p[0];

    // e-phase mapping: 4 i-rows (ty in [0,32)) x 4 j-cols (tx in [0,16))
    const int tx = t & 15;
    const int ty = t >> 4;
    // PV mapping: 8 rows (vy in [0,16)) x 4 d (vx in [0,32))
    const int vx = t & 31;
    const int vy = t >> 5;

    // ---- stage attention vectors ----
    {
        const int k = t >> 7;
        const int d = t & 127;
        const float* ap = (k == 0) ? a0 : (k == 1) ? a1 : (k == 2) ? a2 : a3;
        sh_a[k][d] = ap[d];
    }
    // ---- stage h_i tile (128 rows), patch d=127 with time embedding ----
    {
        const float* src  = hidden + ((size_t)b * kN + i0) * kD;
        const float* tsrc = times  + (size_t)b * kN + i0;
#pragma unroll
        for (int k = 0; k < 8; ++k) {
            const int flat = t + k * 512;
            const int row = flat >> 5;
            const int c4  = flat & 31;
            float4 v = *reinterpret_cast<const float4*>(src + row * kD + c4 * 4);
            if (c4 == 31) v.w = p0 * __expf(-tsrc[row]) + p1;
            *reinterpret_cast<float4*>(&sh_hi[row][c4 * 4]) = v;
        }
    }

    float m_r[4], l_r[4];
#pragma unroll
    for (int ii = 0; ii < 4; ++ii) { m_r[ii] = kNegInf; l_r[ii] = 0.f; }
    float o_acc[8][4];
#pragma unroll
    for (int r = 0; r < 8; ++r)
#pragma unroll
        for (int w = 0; w < 4; ++w) o_acc[r][w] = 0.f;

    for (int jt = 0; jt < 8; ++jt) {
        __syncthreads();   // prev PV done -> safe to overwrite sh_hj
        // ---- stage h_j tile (64 rows), patch d=127 ----
#pragma unroll
        for (int k = 0; k < 4; ++k) {
            const int flat = t + k * 512;
            const int row = flat >> 5;
            const int c4  = flat & 31;
            const float* src = hidden + ((size_t)b * kN + jt * TJ + row) * kD + c4 * 4;
            float4 v = *reinterpret_cast<const float4*>(src);
            if (c4 == 31) v.w = p0 * __expf(-times[(size_t)b * kN + jt * TJ + row]) + p1;
            *reinterpret_cast<float4*>(&sh_hj[row][c4 * 4]) = v;
        }
        // adj codes for this thread's 4x4 pair tile (coalesced int4 rows)
        int adjv[4][4];
#pragma unroll
        for (int ii = 0; ii < 4; ++ii) {
            const int* ap = adj + ((size_t)b * kN + i0 + ty * 4 + ii) * kN + jt * TJ + tx * 4;
            const int4 av = *reinterpret_cast<const int4*>(ap);
            adjv[ii][0] = av.x; adjv[ii][1] = av.y; adjv[ii][2] = av.z; adjv[ii][3] = av.w;
        }
        __syncthreads();   // sh_hj (and first-iter sh_hi/sh_a) ready

        // ---- e-phase: accumulate all 4 relation scores ----
        float acc[4][4][4];
#pragma unroll
        for (int ii = 0; ii < 4; ++ii)
#pragma unroll
            for (int jj = 0; jj < 4; ++jj)
#pragma unroll
                for (int k = 0; k < 4; ++k) acc[ii][jj][k] = 0.f;

#pragma unroll 2
        for (int dc = 0; dc < 32; ++dc) {
            float4 av4[4], hi4[4], hj4[4];
#pragma unroll
            for (int k = 0; k < 4; ++k)
                av4[k] = *reinterpret_cast<const float4*>(&sh_a[k][dc * 4]);
#pragma unroll
            for (int ii = 0; ii < 4; ++ii)
                hi4[ii] = *reinterpret_cast<const float4*>(&sh_hi[ty * 4 + ii][dc * 4]);
#pragma unroll
            for (int jj = 0; jj < 4; ++jj)
                hj4[jj] = *reinterpret_cast<const float4*>(&sh_hj[tx * 4 + jj][dc * 4]);
#pragma unroll
            for (int dd = 0; dd < 4; ++dd) {
#pragma unroll
                for (int ii = 0; ii < 4; ++ii) {
                    const float hiv = reinterpret_cast<const float*>(&hi4[ii])[dd];
#pragma unroll
                    for (int jj = 0; jj < 4; ++jj) {
                        const float prod = hiv * reinterpret_cast<const float*>(&hj4[jj])[dd];
#pragma unroll
                        for (int k = 0; k < 4; ++k)
                            acc[ii][jj][k] = fmaf(prod,
                                reinterpret_cast<const float*>(&av4[k])[dd],
                                acc[ii][jj][k]);
                    }
                }
            }
        }

        // ---- select by adj, leaky_relu, mask ----
        float vv[4][4];
#pragma unroll
        for (int ii = 0; ii < 4; ++ii)
#pragma unroll
            for (int jj = 0; jj < 4; ++jj) {
                const int k = adjv[ii][jj];
                const float e = (k == 1) ? acc[ii][jj][0]
                              : (k == 2) ? acc[ii][jj][1]
                              : (k == 3) ? acc[ii][jj][2]
                              :            acc[ii][jj][3];
                const float lr = fmaxf(e, 0.f) + kAlpha * fminf(e, 0.f);
                vv[ii][jj] = (k == 0) ? kNegInf : lr;
            }

        // ---- online softmax (row = 16 lanes x 4 jj) ----
#pragma unroll
        for (int ii = 0; ii < 4; ++ii) {
            float rm = fmaxf(fmaxf(vv[ii][0], vv[ii][1]), fmaxf(vv[ii][2], vv[ii][3]));
            rm = fmaxf(rm, __shfl_xor(rm, 1));
            rm = fmaxf(rm, __shfl_xor(rm, 2));
            rm = fmaxf(rm, __shfl_xor(rm, 4));
            rm = fmaxf(rm, __shfl_xor(rm, 8));
            const float mnew = fmaxf(m_r[ii], rm);
            const float sc = __expf(m_r[ii] - mnew);
            const float e0 = __expf(vv[ii][0] - mnew);
            const float e1 = __expf(vv[ii][1] - mnew);
            const float e2 = __expf(vv[ii][2] - mnew);
            const float e3 = __expf(vv[ii][3] - mnew);
            float ps = (e0 + e1) + (e2 + e3);
            ps += __shfl_xor(ps, 1);
            ps += __shfl_xor(ps, 2);
            ps += __shfl_xor(ps, 4);
            ps += __shfl_xor(ps, 8);
            l_r[ii] = l_r[ii] * sc + ps;
            m_r[ii] = mnew;
            *reinterpret_cast<float4*>(&sh_p[ty * 4 + ii][tx * 4]) =
                make_float4(e0, e1, e2, e3);
            if (tx == 0) {
                sh_scale[ty * 4 + ii] = sc;
                if (jt == 7) sh_l[ty * 4 + ii] = l_r[ii];
            }
        }
        __syncthreads();   // sh_p / sh_scale ready

        // ---- PV: o = o*scale + p @ h_j  (remapped: 8 rows x 4 d) ----
#pragma unroll
        for (int r = 0; r < 8; ++r) {
            const float s = sh_scale[vy * 8 + r];
#pragma unroll
            for (int w = 0; w < 4; ++w) o_acc[r][w] *= s;
        }
#pragma unroll 2
        for (int j4 = 0; j4 < 16; ++j4) {
            float4 hv[4];
#pragma unroll
            for (int q = 0; q < 4; ++q)
                hv[q] = *reinterpret_cast<const float4*>(&sh_hj[j4 * 4 + q][vx * 4]);
#pragma unroll
            for (int r = 0; r < 8; ++r) {
                const float4 p4 = *reinterpret_cast<const float4*>(&sh_p[vy * 8 + r][j4 * 4]);
                const float pv[4] = {p4.x, p4.y, p4.z, p4.w};
#pragma unroll
                for (int q = 0; q < 4; ++q) {
                    const float* hq = reinterpret_cast<const float*>(&hv[q]);
#pragma unroll
                    for (int w = 0; w < 4; ++w)
                        o_acc[r][w] = fmaf(pv[q], hq[w], o_acc[r][w]);
                }
            }
        }
    }

    // ---- epilogue: divide by softmax denom, store ----
    // sh_l was written during jt==7 e-phase and synced before the last PV.
#pragma unroll
    for (int r = 0; r < 8; ++r) {
        const int row = vy * 8 + r;
        const float inv = 1.0f / sh_l[row];
        float4 res;
        res.x = o_acc[r][0] * inv;
        res.y = o_acc[r][1] * inv;
        res.z = o_acc[r][2] * inv;
        res.w = o_acc[r][3] * inv;
        *reinterpret_cast<float4*>(out + ((size_t)b * kN + i0 + row) * kD + vx * 4) = res;
    }
}

extern "C" void kernel_launch(void* const* d_in, const int* in_sizes, int n_in,
                              void* d_out, int out_size, void* d_ws, size_t ws_size,
                              hipStream_t stream) {
    const float* hidden = (const float*)d_in[0];
    const int*   adj    = (const int*)d_in[1];
    const float* times  = (const float*)d_in[2];
    const float* a0 = (const float*)d_in[3];
    const float* a1 = (const float*)d_in[4];
    const float* a2 = (const float*)d_in[5];
    const float* a3 = (const float*)d_in[6];
    const float* p0 = (const float*)d_in[7];
    const float* p1 = (const float*)d_in[8];
    float* outp = (float*)d_out;
    (void)in_sizes; (void)n_in; (void)out_size; (void)d_ws; (void)ws_size;

    gat_flash_f32<<<dim3(kB * (kN / TI)), dim3(512), 0, stream>>>(
        hidden, adj, times, a0, a1, a2, a3, p0, p1, outp);
}

// Round 10
// 214.307 us; speedup vs baseline: 2.0758x; 2.0758x over previous
//
#include <hip/hip_runtime.h>
#include <hip/hip_bf16.h>

// LocalAggregator fused kernel, round 2 design rev B (resubmit — R2..R9 all
// infra failures; rev B fixed the sh_hjf LDS stride bug: rows are 128 floats
// wide, stride must be >=128, now 132; the old [68] stride aliased adjacent
// rows and would have corrupted PV).
//   e-phase on fp16 MFMA: E_k[i][j] = sum_d (h_i[d]*a_k[d]) * h_j[d]
//   A-frags (h_i*a_k -> fp16) resident in registers across the j-loop.
//   B (h_j fp16) staged in LDS. adj-select + leaky_relu + online softmax on
//   MFMA D-fragments (row=(lane>>4)*4+reg, col=lane&15 -- m89-verified).
//   PV kept on the fp32 VALU path (separate pipe, overlaps MFMA).

typedef _Float16 half8  __attribute__((ext_vector_type(8)));
typedef _Float16 half4v __attribute__((ext_vector_type(4)));
typedef float    f32x4  __attribute__((ext_vector_type(4)));

namespace {
constexpr int kB = 64;
constexpr int kN = 512;
constexpr int kD = 128;
constexpr int TI = 128;         // i-rows per block (8 waves x 16)
constexpr int TJ = 64;          // j-cols per tile
constexpr float kNegInf = -9e15f;
constexpr float kAlpha  = 0.2f;
}

__launch_bounds__(512, 2)
__global__ void gat_mfma_f16(const float* __restrict__ hidden,
                             const int*   __restrict__ adj,
                             const float* __restrict__ times,
                             const float* __restrict__ a0,
                             const float* __restrict__ a1,
                             const float* __restrict__ a2,
                             const float* __restrict__ a3,
                             const float* __restrict__ p0p,
                             const float* __restrict__ p1p,
                             float* __restrict__ out)
{
    __shared__ _Float16 sh_hjh[TJ][136];  // fp16 h_j for MFMA B-frags (8-half pad)
    __shared__ float    sh_hjf[TJ][132];  // fp32 h_j for VALU PV (128 cols + 4 pad)
    __shared__ float    sh_p  [TI][68];   // exp(P), cols are j-index 0..63 (+4 pad)
    __shared__ float    sh_scale[TI];
    __shared__ float    sh_l[TI];

    const int t    = threadIdx.x;
    const int b    = blockIdx.x >> 2;
    const int i0   = (blockIdx.x & 3) * TI;
    const int lane = t & 63;
    const int w    = t >> 6;        // wave 0..7, owns i-rows [w*16, w*16+16)
    const int g    = lane >> 4;     // lanegroup 0..3
    const int c    = lane & 15;

    const float p0 = p0p[0];
    const float p1 = p1p[0];

    // PV mapping (verified R1 structure): 8 rows x 4 d per thread
    const int vx = t & 31;
    const int vy = t >> 5;

    // ---- build resident A-fragments: af[kc][k] = fp16(h_i[d]*a_k[d]) ----
    // A layout: row = c (lane&15), k-slot = g*8 + r within 32-chunk kc.
    half8 af[4][4];
    {
        const int arow = i0 + w * 16 + c;
        const float* hrow = hidden + ((size_t)b * kN + arow) * kD;
        const float te = p0 * __expf(-times[(size_t)b * kN + arow]) + p1;
#pragma unroll
        for (int kc = 0; kc < 4; ++kc) {
            const int d0 = kc * 32 + g * 8;
            f32x4 h0 = *reinterpret_cast<const f32x4*>(hrow + d0);
            f32x4 h1 = *reinterpret_cast<const f32x4*>(hrow + d0 + 4);
            if (d0 + 7 == 127) h1[3] = te;
            const float hv[8] = {h0[0], h0[1], h0[2], h0[3],
                                 h1[0], h1[1], h1[2], h1[3]};
            const float* aks[4] = {a0, a1, a2, a3};
#pragma unroll
            for (int k = 0; k < 4; ++k) {
                f32x4 A0 = *reinterpret_cast<const f32x4*>(aks[k] + d0);
                f32x4 A1 = *reinterpret_cast<const f32x4*>(aks[k] + d0 + 4);
                const float av[8] = {A0[0], A0[1], A0[2], A0[3],
                                     A1[0], A1[1], A1[2], A1[3]};
                half8 v;
#pragma unroll
                for (int r = 0; r < 8; ++r) v[r] = (_Float16)(hv[r] * av[r]);
                af[kc][k] = v;
            }
        }
    }

    float m_r[4], l_r[4];
#pragma unroll
    for (int q = 0; q < 4; ++q) { m_r[q] = kNegInf; l_r[q] = 0.f; }
    float o_acc[8][4];
#pragma unroll
    for (int r = 0; r < 8; ++r)
#pragma unroll
        for (int d = 0; d < 4; ++d) o_acc[r][d] = 0.f;

    for (int jt = 0; jt < 8; ++jt) {
        __syncthreads();   // prev PV done -> safe to overwrite sh_hj*/sh_p

        // ---- stage h_j tile: fp32 (PV) + fp16 (MFMA), patch d=127 ----
#pragma unroll
        for (int it = 0; it < 4; ++it) {
            const int flat = t + it * 512;
            const int row  = flat >> 5;
            const int c4   = flat & 31;
            const size_t jrow = (size_t)b * kN + jt * TJ + row;
            f32x4 v = *reinterpret_cast<const f32x4*>(hidden + jrow * kD + c4 * 4);
            if (c4 == 31) v[3] = p0 * __expf(-times[jrow]) + p1;
            *reinterpret_cast<f32x4*>(&sh_hjf[row][c4 * 4]) = v;
            half4v h;
#pragma unroll
            for (int x = 0; x < 4; ++x) h[x] = (_Float16)v[x];
            *reinterpret_cast<half4v*>(&sh_hjh[row][c4 * 4]) = h;
        }

        // ---- adj codes for this lane's D-fragment positions (issued early) ----
        int adjv[4][4];   // [q][jt4], row = w*16 + g*4 + q, col = jt4*16 + c
#pragma unroll
        for (int q = 0; q < 4; ++q)
#pragma unroll
            for (int jt4 = 0; jt4 < 4; ++jt4)
                adjv[q][jt4] = adj[((size_t)b * kN + i0 + w * 16 + g * 4 + q) * kN
                                   + jt * TJ + jt4 * 16 + c];

        __syncthreads();   // sh_hj* ready

        // ---- e-phase: 4 k x 4 j-subtiles x 4 k-chunks of MFMA ----
        f32x4 E[4][4];     // [jt4][k]
#pragma unroll
        for (int jt4 = 0; jt4 < 4; ++jt4)
#pragma unroll
            for (int k = 0; k < 4; ++k) E[jt4][k] = (f32x4)0.f;

#pragma unroll
        for (int kc = 0; kc < 4; ++kc) {
#pragma unroll
            for (int jt4 = 0; jt4 < 4; ++jt4) {
                // B layout: col = c, k-slot = g*8 + r  (same k-map as A)
                half8 bf = *reinterpret_cast<const half8*>(
                    &sh_hjh[jt4 * 16 + c][kc * 32 + g * 8]);
#pragma unroll
                for (int k = 0; k < 4; ++k)
                    E[jt4][k] = __builtin_amdgcn_mfma_f32_16x16x32_f16(
                        af[kc][k], bf, E[jt4][k], 0, 0, 0);
            }
        }

        // ---- select by adj, leaky_relu, online softmax (per row q) ----
#pragma unroll
        for (int q = 0; q < 4; ++q) {
            float vvq[4];
#pragma unroll
            for (int jt4 = 0; jt4 < 4; ++jt4) {
                const int k = adjv[q][jt4];
                const float e = (k == 1) ? E[jt4][0][q]
                              : (k == 2) ? E[jt4][1][q]
                              : (k == 3) ? E[jt4][2][q]
                              :            E[jt4][3][q];
                const float lr = fmaxf(e, 0.f) + kAlpha * fminf(e, 0.f);
                vvq[jt4] = (k == 0) ? kNegInf : lr;
            }
            float rm = fmaxf(fmaxf(vvq[0], vvq[1]), fmaxf(vvq[2], vvq[3]));
            rm = fmaxf(rm, __shfl_xor(rm, 1));
            rm = fmaxf(rm, __shfl_xor(rm, 2));
            rm = fmaxf(rm, __shfl_xor(rm, 4));
            rm = fmaxf(rm, __shfl_xor(rm, 8));
            const float mnew = fmaxf(m_r[q], rm);
            const float sc = __expf(m_r[q] - mnew);
            float pq[4];
#pragma unroll
            for (int jt4 = 0; jt4 < 4; ++jt4) pq[jt4] = __expf(vvq[jt4] - mnew);
            float ps = (pq[0] + pq[1]) + (pq[2] + pq[3]);
            ps += __shfl_xor(ps, 1);
            ps += __shfl_xor(ps, 2);
            ps += __shfl_xor(ps, 4);
            ps += __shfl_xor(ps, 8);
            l_r[q] = l_r[q] * sc + ps;
            m_r[q] = mnew;
            const int row = w * 16 + g * 4 + q;
#pragma unroll
            for (int jt4 = 0; jt4 < 4; ++jt4)
                sh_p[row][jt4 * 16 + c] = pq[jt4];
            if (c == 0) {
                sh_scale[row] = sc;
                if (jt == 7) sh_l[row] = l_r[q];
            }
        }
        __syncthreads();   // sh_p / sh_scale ready

        // ---- PV (fp32 VALU, verified R1 structure): o = o*sc + p @ h_j ----
#pragma unroll
        for (int r = 0; r < 8; ++r) {
            const float s = sh_scale[vy * 8 + r];
#pragma unroll
            for (int d = 0; d < 4; ++d) o_acc[r][d] *= s;
        }
#pragma unroll 2
        for (int j4 = 0; j4 < 16; ++j4) {
            f32x4 hv[4];
#pragma unroll
            for (int qq = 0; qq < 4; ++qq)
                hv[qq] = *reinterpret_cast<const f32x4*>(&sh_hjf[j4 * 4 + qq][vx * 4]);
#pragma unroll
            for (int r = 0; r < 8; ++r) {
                const f32x4 p4 = *reinterpret_cast<const f32x4*>(&sh_p[vy * 8 + r][j4 * 4]);
#pragma unroll
                for (int qq = 0; qq < 4; ++qq) {
#pragma unroll
                    for (int d = 0; d < 4; ++d)
                        o_acc[r][d] = fmaf(p4[qq], hv[qq][d], o_acc[r][d]);
                }
            }
        }
    }

    // ---- epilogue: divide by softmax denom, store ----
#pragma unroll
    for (int r = 0; r < 8; ++r) {
        const int row = vy * 8 + r;
        const float inv = 1.0f / sh_l[row];
        f32x4 res;
#pragma unroll
        for (int d = 0; d < 4; ++d) res[d] = o_acc[r][d] * inv;
        *reinterpret_cast<f32x4*>(out + ((size_t)b * kN + i0 + row) * kD + vx * 4) = res;
    }
}

extern "C" void kernel_launch(void* const* d_in, const int* in_sizes, int n_in,
                              void* d_out, int out_size, void* d_ws, size_t ws_size,
                              hipStream_t stream) {
    const float* hidden = (const float*)d_in[0];
    const int*   adj    = (const int*)d_in[1];
    const float* times  = (const float*)d_in[2];
    const float* a0 = (const float*)d_in[3];
    const float* a1 = (const float*)d_in[4];
    const float* a2 = (const float*)d_in[5];
    const float* a3 = (const float*)d_in[6];
    const float* p0 = (const float*)d_in[7];
    const float* p1 = (const float*)d_in[8];
    float* outp = (float*)d_out;
    (void)in_sizes; (void)n_in; (void)out_size; (void)d_ws; (void)ws_size;

    gat_mfma_f16<<<dim3(kB * (kN / TI)), dim3(512), 0, stream>>>(
        hidden, adj, times, a0, a1, a2, a3, p0, p1, outp);
}